// Round 6
// baseline (636.145 us; speedup 1.0000x reference)
//
#include <hip/hip_runtime.h>

#define HH 8
#define TT 4096
#define DD 128
#define NKT 128        // key tiles (TT/32)
#define PS 36          // P row stride in shorts
#define NEG_BIG (-3.0e38f)

// Workspace layout (shorts): Khi[8 MB] | Klo[8 MB] | Vt[8 MB] = 25.2 MB total.
// Fragment order: frag = 64 lanes x 16 B contiguous (1024 B), so one
// global_load_dwordx4 per lane fetches a whole MFMA B-operand, coalesced.
#define HEAD_FRAG_SHORTS ((size_t)NKT * 8 * 512)   // 1 MB per head per array

typedef __attribute__((ext_vector_type(8)))  short short8;
typedef __attribute__((ext_vector_type(16))) float float16;

__device__ __forceinline__ short bf16_rne(float x) {
    unsigned u = __float_as_uint(x);
    return (short)((u + 0x7fffu + ((u >> 16) & 1u)) >> 16);
}
__device__ __forceinline__ float bf16_f(short s) {
    return __uint_as_float(((unsigned)(unsigned short)s) << 16);
}

// ---------------- prep: fp32 K,V -> bf16 fragments in ws ----------------
__global__ __launch_bounds__(256) void prep_kernel(
    const float* __restrict__ k, const float* __restrict__ v,
    short* __restrict__ khi, short* __restrict__ klo, short* __restrict__ vt)
{
    const int h = blockIdx.x, kt = blockIdx.y, t = threadIdx.x;
    __shared__ float Vs[32][132];                  // 16.9 KB, fp32 V tile

    #pragma unroll
    for (int it = 0; it < 4; ++it) {               // stage V tile 32 keys x 128 dims
        const int f = t + it * 256;
        const int j = f >> 5, c = f & 31;
        *(float4*)&Vs[j][c * 4] =
            *(const float4*)(v + ((size_t)(h * TT + kt * 32 + j)) * DD + c * 4);
    }

    // K fragments: B[n=key m][k-dim = ks*16 + hf*8 + e]
    #pragma unroll
    for (int it = 0; it < 2; ++it) {
        const int idx = t + it * 256;              // [0,512)
        const int ks = idx >> 6, ln = idx & 63, m = ln & 31, hf = ln >> 5;
        const float* src = k + ((size_t)(h * TT + kt * 32 + m)) * DD + ks * 16 + hf * 8;
        const float4 a = *(const float4*)src;
        const float4 b = *(const float4*)(src + 4);
        const float f8[8] = {a.x, a.y, a.z, a.w, b.x, b.y, b.z, b.w};
        short8 hi8, lo8;
        #pragma unroll
        for (int e = 0; e < 8; ++e) {
            const short hi_ = bf16_rne(f8[e]);
            hi8[e] = hi_;
            lo8[e] = bf16_rne(f8[e] - bf16_f(hi_));
        }
        const size_t off = ((size_t)((h * NKT + kt) * 8 + ks)) * 512 + ln * 8;
        *(short8*)(khi + off) = hi8;
        *(short8*)(klo + off) = lo8;
    }
    __syncthreads();

    // V fragments: B[n=dim nt*32+m][k-key = ks2*16 + hf*8 + e]
    #pragma unroll
    for (int it = 0; it < 2; ++it) {
        const int idx = t + it * 256;              // [0,512)
        const int nt = idx >> 7, ks2 = (idx >> 6) & 1, ln = idx & 63;
        const int m = ln & 31, hf = ln >> 5, n = nt * 32 + m;
        short8 o;
        #pragma unroll
        for (int e = 0; e < 8; ++e)
            o[e] = bf16_rne(Vs[ks2 * 16 + hf * 8 + e][n]);
        const size_t off = ((size_t)(((h * NKT + kt) * 4 + nt) * 2 + ks2)) * 512 + ln * 8;
        *(short8*)(vt + off) = o;
    }
}

// ---------------- attention: barrier-free, fragment-direct ----------------
__global__ __launch_bounds__(64) void attn_kernel(
    const float* __restrict__ q,
    const short* __restrict__ khi, const short* __restrict__ klo,
    const short* __restrict__ vt, float* __restrict__ out)
{
    const int h = blockIdx.x;                          // head -> XCD L2 pinning
    const int g = (int)(gridDim.y - 1) - (int)blockIdx.y;  // big row-tiles first
    const int growb = g * 32;
    const int ln = threadIdx.x, m = ln & 31, hf = ln >> 5;

    __shared__ short Pl[32][PS];                       // wave-private, 2.3 KB

    const short* khiH = khi + (size_t)h * HEAD_FRAG_SHORTS;
    const short* kloH = klo + (size_t)h * HEAD_FRAG_SHORTS;
    const short* vtH  = vt  + (size_t)h * HEAD_FRAG_SHORTS;

    // Q resident as A-fragments, bf16 hi/lo (same placement as round 5)
    short8 qhi[8], qlo[8];
    const float* qrow = q + ((size_t)(h * TT + growb + m)) * DD;
    #pragma unroll
    for (int ks = 0; ks < 8; ++ks) {
        const float4 a = *(const float4*)(qrow + ks * 16 + hf * 8);
        const float4 b = *(const float4*)(qrow + ks * 16 + hf * 8 + 4);
        const float f8[8] = {a.x, a.y, a.z, a.w, b.x, b.y, b.z, b.w};
        #pragma unroll
        for (int j = 0; j < 8; ++j) {
            const short hi_ = bf16_rne(f8[j]);
            qhi[ks][j] = hi_;
            qlo[ks][j] = bf16_rne(f8[j] - bf16_f(hi_));
        }
    }

    float16 Oa[4];
    float lsum[16];
    #pragma unroll
    for (int nt = 0; nt < 4; ++nt)
        #pragma unroll
        for (int r = 0; r < 16; ++r) Oa[nt][r] = 0.f;
    #pragma unroll
    for (int r = 0; r < 16; ++r) lsum[r] = 0.f;
    float mrun = NEG_BIG;

    for (int kt = 0; kt <= g; ++kt) {
        const bool diag = (kt == g);

        // ---- QK^T: fragment-direct B loads, two parity acc chains ----
        float16 a0, a1;
        #pragma unroll
        for (int r = 0; r < 16; ++r) { a0[r] = 0.f; a1[r] = 0.f; }
        #pragma unroll
        for (int ks = 0; ks < 8; ++ks) {
            union { int4 i4; short8 s; } bh, bl;
            const size_t fo = ((size_t)(kt * 8 + ks)) * 512 + ln * 8;
            bh.i4 = *(const int4*)(khiH + fo);
            bl.i4 = *(const int4*)(kloH + fo);
            if (ks & 1) {
                a1 = __builtin_amdgcn_mfma_f32_32x32x16_bf16(qhi[ks], bh.s, a1, 0, 0, 0);
                a1 = __builtin_amdgcn_mfma_f32_32x32x16_bf16(qlo[ks], bh.s, a1, 0, 0, 0);
                a1 = __builtin_amdgcn_mfma_f32_32x32x16_bf16(qhi[ks], bl.s, a1, 0, 0, 0);
            } else {
                a0 = __builtin_amdgcn_mfma_f32_32x32x16_bf16(qhi[ks], bh.s, a0, 0, 0, 0);
                a0 = __builtin_amdgcn_mfma_f32_32x32x16_bf16(qlo[ks], bh.s, a0, 0, 0, 0);
                a0 = __builtin_amdgcn_mfma_f32_32x32x16_bf16(qhi[ks], bl.s, a0, 0, 0, 0);
            }
        }
        float16 acc;
        #pragma unroll
        for (int r = 0; r < 16; ++r) acc[r] = a0[r] + a1[r];

        // ---- causal mask only on the diagonal tile ----
        if (diag) {
            #pragma unroll
            for (int r = 0; r < 16; ++r)
                if (m > 4 * hf + (r & 3) + 8 * (r >> 2)) acc[r] = NEG_BIG;
        }

        // ---- tile-max online softmax (all state in registers) ----
        float tm = acc[0];
        #pragma unroll
        for (int r = 1; r < 16; ++r) tm = fmaxf(tm, acc[r]);
        #pragma unroll
        for (int off = 32; off > 0; off >>= 1)
            tm = fmaxf(tm, __shfl_xor(tm, off, 64));
        const float mnew  = fmaxf(mrun, tm);
        const float alpha = __expf(mrun - mnew);       // first tile: 0
        mrun = mnew;
        if (alpha != 1.0f) {                           // wave-uniform branch
            #pragma unroll
            for (int r = 0; r < 16; ++r) {
                Oa[0][r] *= alpha; Oa[1][r] *= alpha;
                Oa[2][r] *= alpha; Oa[3][r] *= alpha;
                lsum[r]  *= alpha;
            }
        }
        #pragma unroll
        for (int r = 0; r < 16; ++r) {
            const float p = __expf(acc[r] - mnew);     // masked -> 0
            lsum[r] += p;
            Pl[(r & 3) + 8 * (r >> 2) + 4 * hf][m] = bf16_rne(p);
        }
        // no barrier: single-wave block, same-wave DS ops are ordered

        // ---- PV: fragment-direct V loads ----
        #pragma unroll
        for (int ks2 = 0; ks2 < 2; ++ks2) {
            union { int2 d[2]; short8 s; } up;         // A[m=row][k=key]
            const int pe = ks2 * 16 + hf * 8;
            up.d[0] = *(const int2*)&Pl[m][pe];
            up.d[1] = *(const int2*)&Pl[m][pe + 4];
            #pragma unroll
            for (int nt = 0; nt < 4; ++nt) {
                union { int4 i4; short8 s; } uv;
                uv.i4 = *(const int4*)(vtH + ((size_t)((kt * 4 + nt) * 2 + ks2)) * 512 + ln * 8);
                Oa[nt] = __builtin_amdgcn_mfma_f32_32x32x16_bf16(up.s, uv.s, Oa[nt], 0, 0, 0);
            }
        }
    }

    // ---- epilogue: l-reduce across 32 key columns, write out ----
    #pragma unroll
    for (int r = 0; r < 16; ++r) {
        float s = lsum[r];
        #pragma unroll
        for (int off = 16; off > 0; off >>= 1)
            s += __shfl_xor(s, off, 64);
        lsum[r] = 1.f / s;
    }
    #pragma unroll
    for (int r = 0; r < 16; ++r) {
        const int grow = growb + 4 * hf + (r & 3) + 8 * (r >> 2);
        float* op = out + ((size_t)(h * TT + grow)) * DD + m;
        op[0]  = Oa[0][r] * lsum[r];
        op[32] = Oa[1][r] * lsum[r];
        op[64] = Oa[2][r] * lsum[r];
        op[96] = Oa[3][r] * lsum[r];
    }
}

extern "C" void kernel_launch(void* const* d_in, const int* in_sizes, int n_in,
                              void* d_out, int out_size, void* d_ws, size_t ws_size,
                              hipStream_t stream) {
    const float* q = (const float*)d_in[0];
    const float* k = (const float*)d_in[1];
    const float* v = (const float*)d_in[2];
    float* out = (float*)d_out;

    short* khi = (short*)d_ws;                          // needs 25.2 MB of ws
    short* klo = khi + (size_t)HH * HEAD_FRAG_SHORTS;
    short* vt  = klo + (size_t)HH * HEAD_FRAG_SHORTS;

    prep_kernel<<<dim3(HH, NKT), dim3(256), 0, stream>>>(k, v, khi, klo, vt);
    attn_kernel<<<dim3(HH, NKT), dim3(64), 0, stream>>>(q, khi, klo, vt, out);
}

// Round 9
// 209.269 us; speedup vs baseline: 3.0398x; 3.0398x over previous
//
#include <hip/hip_runtime.h>

#define HH 8
#define TT 4096
#define DD 128
#define NKT 128              // 32-key tiles per head
#define PS 36                // P row stride in shorts (72 B rows)
#define NEG_BIG (-3.0e38f)

// ws (shorts): Khi[8.4MB] | Klo[8.4MB] | Vt[8.4MB] — proven available in round 6
#define HEAD_FRAG_SHORTS ((size_t)NKT * 8 * 512)

typedef __attribute__((ext_vector_type(8)))  short short8;
typedef __attribute__((ext_vector_type(16))) float float16;

__device__ __forceinline__ short bf16_rne(float x) {
    unsigned u = __float_as_uint(x);
    return (short)((u + 0x7fffu + ((u >> 16) & 1u)) >> 16);
}
__device__ __forceinline__ float bf16_f(short s) {
    return __uint_as_float(((unsigned)(unsigned short)s) << 16);
}

// ---------------- prep: fp32 K,V -> bf16 hi/lo fragments (round-6 verified) ----------------
__global__ __launch_bounds__(256) void prep_kernel(
    const float* __restrict__ k, const float* __restrict__ v,
    short* __restrict__ khi, short* __restrict__ klo, short* __restrict__ vt)
{
    const int h = blockIdx.x, kt = blockIdx.y, t = threadIdx.x;
    __shared__ float Vs[32][132];

    #pragma unroll
    for (int it = 0; it < 4; ++it) {               // stage V tile 32 keys x 128 dims
        const int f = t + it * 256, j = f >> 5, c = f & 31;
        *(float4*)&Vs[j][c * 4] =
            *(const float4*)(v + ((size_t)(h * TT + kt * 32 + j)) * DD + c * 4);
    }
    // K fragments: B[n=key m][k-dim = ks*16 + hf*8 + e]
    #pragma unroll
    for (int it = 0; it < 2; ++it) {
        const int idx = t + it * 256;
        const int ks = idx >> 6, ln = idx & 63, m = ln & 31, hf = ln >> 5;
        const float* src = k + ((size_t)(h * TT + kt * 32 + m)) * DD + ks * 16 + hf * 8;
        const float4 a = *(const float4*)src;
        const float4 b = *(const float4*)(src + 4);
        const float f8[8] = {a.x, a.y, a.z, a.w, b.x, b.y, b.z, b.w};
        short8 hi8, lo8;
        #pragma unroll
        for (int e = 0; e < 8; ++e) {
            const short hi_ = bf16_rne(f8[e]);
            hi8[e] = hi_;
            lo8[e] = bf16_rne(f8[e] - bf16_f(hi_));
        }
        const size_t off = ((size_t)((h * NKT + kt) * 8 + ks)) * 512 + ln * 8;
        *(short8*)(khi + off) = hi8;
        *(short8*)(klo + off) = lo8;
    }
    __syncthreads();
    // V fragments: B[n=dim nt*32+m][k-key = ks2*16 + hf*8 + e]
    #pragma unroll
    for (int it = 0; it < 2; ++it) {
        const int idx = t + it * 256;
        const int nt = idx >> 7, ks2 = (idx >> 6) & 1, ln = idx & 63;
        const int m = ln & 31, hf = ln >> 5, n = nt * 32 + m;
        short8 o;
        #pragma unroll
        for (int e = 0; e < 8; ++e)
            o[e] = bf16_rne(Vs[ks2 * 16 + hf * 8 + e][n]);
        *(short8*)(vt + ((size_t)(((h * NKT + kt) * 4 + nt) * 2 + ks2)) * 512 + ln * 8) = o;
    }
}

// ------- attention: 4-wave in-block split-K, round-6-verified bf16 math -------
__global__ __launch_bounds__(256, 2) void attn_kernel(
    const float* __restrict__ q,
    const short* __restrict__ khi, const short* __restrict__ klo,
    const short* __restrict__ vt, float* __restrict__ out)
{
    const int h = blockIdx.x;                          // head -> XCD L2 pinning
    const int g = (int)(gridDim.y - 1) - (int)blockIdx.y;  // big row-tiles first
    const int growb = g * 32;
    const int t = threadIdx.x, w = t >> 6, ln = t & 63, m = ln & 31, hf = ln >> 5;

    __shared__ short Pl[4][32][PS];                    // wave-private P slabs (9.2 KB)
    __shared__ float OC[4][32][36];                    // combine chunk buffer (18.4 KB)
    __shared__ float Lw[4][32];
    __shared__ float Mw[4];

    const short* khiH = khi + (size_t)h * HEAD_FRAG_SHORTS;
    const short* kloH = klo + (size_t)h * HEAD_FRAG_SHORTS;
    const short* vtH  = vt  + (size_t)h * HEAD_FRAG_SHORTS;

    // Q resident as bf16 hi/lo A-fragments (round-5/6 verified)
    short8 qhi[8], qlo[8];
    const float* qrow = q + ((size_t)(h * TT + growb + m)) * DD;
    #pragma unroll
    for (int ks = 0; ks < 8; ++ks) {
        const float4 a = *(const float4*)(qrow + ks * 16 + hf * 8);
        const float4 b = *(const float4*)(qrow + ks * 16 + hf * 8 + 4);
        const float f8[8] = {a.x, a.y, a.z, a.w, b.x, b.y, b.z, b.w};
        #pragma unroll
        for (int j = 0; j < 8; ++j) {
            const short hi_ = bf16_rne(f8[j]);
            qhi[ks][j] = hi_;
            qlo[ks][j] = bf16_rne(f8[j] - bf16_f(hi_));
        }
    }

    float16 Oa[4];
    float ls[16];
    #pragma unroll
    for (int nt = 0; nt < 4; ++nt)
        #pragma unroll
        for (int r = 0; r < 16; ++r) Oa[nt][r] = 0.f;
    #pragma unroll
    for (int r = 0; r < 16; ++r) ls[r] = 0.f;
    float mrun = NEG_BIG;

    for (int kt = w; kt <= g; kt += 4) {               // split-K: wave w owns kt≡w (mod 4)
        // V fragment loads issued early; consumed after QK+softmax
        int4 vb[8];
        #pragma unroll
        for (int u = 0; u < 8; ++u)
            vb[u] = *(const int4*)(vtH + ((size_t)(kt * 8 + u)) * 512 + ln * 8);

        // ---- QK^T: 8 k-steps x 3 split-MFMAs (round-5/6 verified) ----
        float16 acc;
        #pragma unroll
        for (int r = 0; r < 16; ++r) acc[r] = 0.f;
        #pragma unroll
        for (int ks = 0; ks < 8; ++ks) {
            union { int4 i4; short8 s; } bh, bl;
            const size_t fo = ((size_t)(kt * 8 + ks)) * 512 + ln * 8;
            bh.i4 = *(const int4*)(khiH + fo);
            bl.i4 = *(const int4*)(kloH + fo);
            acc = __builtin_amdgcn_mfma_f32_32x32x16_bf16(qhi[ks], bh.s, acc, 0, 0, 0);
            acc = __builtin_amdgcn_mfma_f32_32x32x16_bf16(qlo[ks], bh.s, acc, 0, 0, 0);
            acc = __builtin_amdgcn_mfma_f32_32x32x16_bf16(qhi[ks], bl.s, acc, 0, 0, 0);
        }

        // causal mask: only the diagonal tile (owned by wave g%4)
        if (kt == g) {
            #pragma unroll
            for (int r = 0; r < 16; ++r)
                if (m > 4 * hf + (r & 3) + 8 * (r >> 2)) acc[r] = NEG_BIG;
        }

        // ---- tile-max online softmax (wave-uniform m) ----
        float tm = acc[0];
        #pragma unroll
        for (int r = 1; r < 16; ++r) tm = fmaxf(tm, acc[r]);
        #pragma unroll
        for (int off = 32; off > 0; off >>= 1)
            tm = fmaxf(tm, __shfl_xor(tm, off, 64));
        const float mnew  = fmaxf(mrun, tm);
        const float alpha = __expf(mrun - mnew);       // first tile: 0
        mrun = mnew;
        if (alpha != 1.0f) {                           // wave-uniform branch
            #pragma unroll
            for (int r = 0; r < 16; ++r) {
                Oa[0][r] *= alpha; Oa[1][r] *= alpha;
                Oa[2][r] *= alpha; Oa[3][r] *= alpha;
                ls[r]    *= alpha;
            }
        }
        #pragma unroll
        for (int r = 0; r < 16; ++r) {
            const float p = __expf(acc[r] - mnew);     // masked -> 0
            ls[r] += p;
            Pl[w][(r & 3) + 8 * (r >> 2) + 4 * hf][m] = bf16_rne(p);
        }
        // no barrier: Pl slab is wave-private; same-wave DS ops are ordered

        // ---- PV (round-5/6 verified) ----
        #pragma unroll
        for (int ks2 = 0; ks2 < 2; ++ks2) {
            union { int2 d[2]; short8 s; } up;
            const int pe = ks2 * 16 + hf * 8;
            up.d[0] = *(const int2*)&Pl[w][m][pe];
            up.d[1] = *(const int2*)&Pl[w][m][pe + 4];
            #pragma unroll
            for (int nt = 0; nt < 4; ++nt) {
                union { int4 i4; short8 s; } uv;
                uv.i4 = vb[nt * 2 + ks2];
                Oa[nt] = __builtin_amdgcn_mfma_f32_32x32x16_bf16(up.s, uv.s, Oa[nt], 0, 0, 0);
            }
        }
    }

    // ---- per-wave l reduce over the 32 key columns ----
    #pragma unroll
    for (int r = 0; r < 16; ++r) {
        float s = ls[r];
        #pragma unroll
        for (int off = 16; off > 0; off >>= 1)
            s += __shfl_xor(s, off, 64);
        ls[r] = s;
    }
    if (m == 0) {
        #pragma unroll
        for (int r = 0; r < 16; ++r)
            Lw[w][4 * hf + (r & 3) + 8 * (r >> 2)] = ls[r];
    }
    if (ln == 0) Mw[w] = mrun;
    __syncthreads();

    // ---- flash-decoding combine across the 4 split-K waves, 32-dim chunks ----
    const int crow = t >> 3, c0 = (t & 7) * 4;
    const float M = fmaxf(fmaxf(Mw[0], Mw[1]), fmaxf(Mw[2], Mw[3]));
    float ee[4];
    #pragma unroll
    for (int u = 0; u < 4; ++u) ee[u] = __expf(Mw[u] - M);  // idle wave -> 0
    const float L = ee[0] * Lw[0][crow] + ee[1] * Lw[1][crow]
                  + ee[2] * Lw[2][crow] + ee[3] * Lw[3][crow];
    const float inv = 1.f / L;
    float* op = out + ((size_t)(h * TT + growb + crow)) * DD;

    #pragma unroll
    for (int nt = 0; nt < 4; ++nt) {
        __syncthreads();                               // OC free for this chunk
        #pragma unroll
        for (int r = 0; r < 16; ++r)
            OC[w][4 * hf + (r & 3) + 8 * (r >> 2)][m] = Oa[nt][r];
        __syncthreads();                               // chunk visible
        float4 s4 = {0.f, 0.f, 0.f, 0.f};
        #pragma unroll
        for (int u = 0; u < 4; ++u) {
            const float4 ov = *(const float4*)&OC[u][crow][c0];
            s4.x += ee[u] * ov.x; s4.y += ee[u] * ov.y;
            s4.z += ee[u] * ov.z; s4.w += ee[u] * ov.w;
        }
        s4.x *= inv; s4.y *= inv; s4.z *= inv; s4.w *= inv;
        *(float4*)(op + nt * 32 + c0) = s4;
    }
}

extern "C" void kernel_launch(void* const* d_in, const int* in_sizes, int n_in,
                              void* d_out, int out_size, void* d_ws, size_t ws_size,
                              hipStream_t stream) {
    const float* q = (const float*)d_in[0];
    const float* k = (const float*)d_in[1];
    const float* v = (const float*)d_in[2];
    float* out = (float*)d_out;

    short* khi = (short*)d_ws;
    short* klo = khi + (size_t)HH * HEAD_FRAG_SHORTS;
    short* vt  = klo + (size_t)HH * HEAD_FRAG_SHORTS;

    prep_kernel<<<dim3(HH, NKT), dim3(256), 0, stream>>>(k, v, khi, klo, vt);
    attn_kernel<<<dim3(HH, NKT), dim3(256), 0, stream>>>(q, khi, klo, vt, out);
}